// Round 19
// baseline (72.512 us; speedup 1.0000x reference)
//
#include <hip/hip_runtime.h>
#include <hip/hip_bf16.h>
#include <stdint.h>

#define GAT_ALPHA 0.2f
#define LOG2E 1.4426950408889634f

typedef __attribute__((ext_vector_type(8))) short bf16x8;
typedef __attribute__((ext_vector_type(8))) _Float16 f16x8;
typedef __attribute__((ext_vector_type(8))) unsigned short ushort8;
typedef __attribute__((ext_vector_type(4))) float f32x4;
typedef __attribute__((ext_vector_type(4))) unsigned int u32x4;

#if __has_builtin(__builtin_amdgcn_exp2f)
#define EXP2F(x) __builtin_amdgcn_exp2f(x)
#else
#define EXP2F(x) exp2f(x)
#endif

// D.lo = bf16(a), D.hi = bf16(b)  (r6-validated)
static __device__ __forceinline__ unsigned int cvt_pk_bf16(float a, float b) {
    unsigned int r;
    asm("v_cvt_pk_bf16_f32 %0, %1, %2" : "=v"(r) : "v"(a), "v"(b));
    return r;
}

// async global->LDS, 16B/lane; dest = wave-uniform base + lane*16 (m104),
// source is PER-LANE (m173 pre-swizzled-source pattern)
static __device__ __forceinline__ void gl16(const void* g, void* l) {
    __builtin_amdgcn_global_load_lds((const __attribute__((address_space(1))) void*)g,
                                     (__attribute__((address_space(3))) void*)l, 16, 0, 0);
}

// ---------------- K0: pack adjacency -> bitmask (r1-validated body) --------
// + blocks 0-31 additionally convert W (r9-validated math). Grid = 65536.
__global__ __launch_bounds__(256) void k_pack_adj(const int* __restrict__ adj,
                                                  unsigned long long* __restrict__ packed,
                                                  int nwords,
                                                  const float* __restrict__ W,
                                                  unsigned short* __restrict__ wbfT) {
    int gid = blockIdx.x * 256 + threadIdx.x;
    int wid = gid >> 6;               // one 64-bit word per wave
    int lane = threadIdx.x & 63;
    if (wid < nwords) {
        int v = adj[(size_t)wid * 64 + lane];
        unsigned long long m = __ballot(v > 0);
        if (lane == 0) packed[wid] = m;
    }
    if (blockIdx.x < 32) {            // fused k_cvtW (r17-validated)
        int idx = (blockIdx.x * 256 + threadIdx.x) * 8;   // over 65536 elements
        int hd = idx >> 8;                                 // head*32 + d
        int i0 = idx & 255;
        int hh = hd >> 5, dd = hd & 31;
        float vv[8];
        #pragma unroll
        for (int k = 0; k < 8; ++k) vv[k] = W[((size_t)hh * 256 + i0 + k) * 32 + dd];
        u32x4 o = { cvt_pk_bf16(vv[0], vv[1]), cvt_pk_bf16(vv[2], vv[3]),
                    cvt_pk_bf16(vv[4], vv[5]), cvt_pk_bf16(vv[6], vv[7]) };
        *(u32x4*)&wbfT[idx] = o;
    }
}

// ---------------- K1: Wh via bf16 MFMA (r17/r18-validated); whT fp16 -------
__global__ __launch_bounds__(256) void k_wh2(const float* __restrict__ hmat,      // [4096][256]
                                             const unsigned short* __restrict__ wbfT, // [8][32][256]
                                             const float* __restrict__ avec,      // [8][64]
                                             float* __restrict__ wh1s,            // [8][4096] *log2e
                                             float* __restrict__ wh2s,            // [8][4096] *log2e
                                             unsigned short* __restrict__ whT) {  // [8][32][4096] fp16
    const int head = blockIdx.y;
    const int nbase = blockIdx.x * 64;
    const int t = threadIdx.x, w = t >> 6, lane = t & 63;
    const int r = lane & 15, q = lane >> 4;
    const int node0 = nbase + w * 16;

    f32x4 acc0 = {0.f, 0.f, 0.f, 0.f};
    f32x4 acc1 = {0.f, 0.f, 0.f, 0.f};
    const float* arow = &hmat[(size_t)(node0 + r) * 256];
    const unsigned short* b0p = &wbfT[((size_t)head * 32 + r) * 256];
    const unsigned short* b1p = b0p + 16 * 256;
    #pragma unroll
    for (int kt = 0; kt < 8; ++kt) {
        const int ko = kt * 32 + q * 8;
        float4 h0 = *(const float4*)&arow[ko];
        float4 h1 = *(const float4*)&arow[ko + 4];
        u32x4 ap = { cvt_pk_bf16(h0.x, h0.y), cvt_pk_bf16(h0.z, h0.w),
                     cvt_pk_bf16(h1.x, h1.y), cvt_pk_bf16(h1.z, h1.w) };
        bf16x8 af = __builtin_bit_cast(bf16x8, ap);
        bf16x8 b0 = *(const bf16x8*)&b0p[ko];
        bf16x8 b1 = *(const bf16x8*)&b1p[ko];
        acc0 = __builtin_amdgcn_mfma_f32_16x16x32_bf16(af, b0, acc0, 0, 0, 0);
        acc1 = __builtin_amdgcn_mfma_f32_16x16x32_bf16(af, b1, acc1, 0, 0, 0);
    }
    // whT in fp16 (RNE; 10-bit mantissa > bf16's 7; |Wh| ~ 20 << 65504)
    auto ph = [](float x) {
        return (unsigned int)__builtin_bit_cast(unsigned short, (_Float16)x);
    };
    unsigned int pk0 = ph(acc0[0]) | (ph(acc0[1]) << 16);
    unsigned int pk1 = ph(acc0[2]) | (ph(acc0[3]) << 16);
    unsigned int pk2 = ph(acc1[0]) | (ph(acc1[1]) << 16);
    unsigned int pk3 = ph(acc1[2]) | (ph(acc1[3]) << 16);
    unsigned long long lo = ((unsigned long long)pk1 << 32) | pk0;
    unsigned long long hi = ((unsigned long long)pk3 << 32) | pk2;
    *(unsigned long long*)&whT[((size_t)head * 32 + r) * 4096 + node0 + q * 4] = lo;
    *(unsigned long long*)&whT[((size_t)head * 32 + 16 + r) * 4096 + node0 + q * 4] = hi;

    float a1lo = avec[head * 64 + r],      a1hi = avec[head * 64 + 16 + r];
    float a2lo = avec[head * 64 + 32 + r], a2hi = avec[head * 64 + 48 + r];
    f32x4 d1, d2;
    #pragma unroll
    for (int i = 0; i < 4; ++i) {
        d1[i] = fmaf(acc0[i], a1lo, acc1[i] * a1hi);
        d2[i] = fmaf(acc0[i], a2lo, acc1[i] * a2hi);
    }
    #pragma unroll
    for (int s = 1; s < 16; s <<= 1) {
        #pragma unroll
        for (int i = 0; i < 4; ++i) {
            d1[i] += __shfl_xor(d1[i], s);
            d2[i] += __shfl_xor(d2[i], s);
        }
    }
    if (r == 0) {
        f32x4 o1 = d1 * LOG2E, o2 = d2 * LOG2E;
        *(f32x4*)&wh1s[(size_t)head * 4096 + node0 + q * 4] = o1;
        *(f32x4*)&wh2s[(size_t)head * 4096 + node0 + q * 4] = o2;
    }
}

// ---------------- K2: fused masked softmax + PV via f16 MFMA ---------------
// r18-validated structure (exp-factored tables, gl16 staging, dbuf, XOR map).
// Single delta: the 256-entry mask LUT ds_read (1 of 5 LDS reads/kk, and the
// 4.1M-conflict source) is replaced by arithmetic mask construction on the
// VALU (which the factorization left with slack). Mask values bit-identical.
__global__ __launch_bounds__(256, 4) void k_attn(const unsigned long long* __restrict__ adj64, // [4096][64]
                                                 const float* __restrict__ wh1s,
                                                 const float* __restrict__ wh2s,
                                                 const unsigned short* __restrict__ whT,
                                                 float* __restrict__ out) {                    // [4096][256]
    const int head = blockIdx.y;
    const int rowbase = blockIdx.x * 32;
    const int t = threadIdx.x;
    const int w = t >> 6;
    const int lane = t & 63;
    const int rt = w & 1;        // row-tile
    const int jh = w >> 1;       // j-half
    const int r = lane & 15;     // MFMA A row / B col
    const int q = lane >> 4;     // k-quarter
    const int row = rowbase + rt * 16 + r;

    __shared__ unsigned short whTl[2][2][32][128];   // [buf][jhalf][d][phys slots]
    __shared__ _Float16 e1t[2][2][128];              // [buf][jhalf][j] exp tables
    __shared__ _Float16 e2t[2][2][128];
    __shared__ float wmxb[4];

    // per-lane pre-swizzled global sources for this wave's 4 staging calls
    const int ghh = w >> 1;          // j-half this wave stages
    const int grg = (w & 1) * 4;     // row-group base
    const unsigned short* gsrc[4];
    #pragma unroll
    for (int c = 0; c < 4; ++c) {
        int d = (grg + c) * 4 + (lane >> 4);
        int p = lane & 15;
        int ls = (p & 8) | ((p ^ d) & 7);
        gsrc[c] = whT + ((size_t)(head * 32 + d)) * 4096 + ghh * 2048 + ls * 8;
    }
    const float* wh2p = &wh2s[(size_t)head * 4096];
    // E-table staging assignment: thread t -> half ehh, j-local ejl
    const int ehh = t >> 7;
    const int ejl = t & 127;
    const float* esrc = wh2p + ehh * 2048 + ejl;

    // per-head max of wh2 (r7-validated prepass) — needed BEFORE E staging
    float lm = -INFINITY;
    #pragma unroll
    for (int kk = 0; kk < 4; ++kk) {
        float4 v = *(const float4*)&wh2p[kk * 1024 + t * 4];
        lm = fmaxf(fmaxf(lm, fmaxf(v.x, v.y)), fmaxf(v.z, v.w));
    }
    #pragma unroll
    for (int s = 1; s < 64; s <<= 1) lm = fmaxf(lm, __shfl_xor(lm, s));
    if (lane == 0) wmxb[w] = lm;
    __syncthreads();   // wmxb ready
    const float wm = fmaxf(fmaxf(wmxb[0], wmxb[1]), fmaxf(wmxb[2], wmxb[3]));

    // per-row constants (log2-scaled). m = max(sm0, a*sm0) -> max(s1,s2)=1.
    const float wh1 = wh1s[(size_t)head * 4096 + row];
    const float sm0 = wh1 + wm;
    const float m = fmaxf(sm0, GAT_ALPHA * sm0);
    const _Float16 s1h = (_Float16)EXP2F(sm0 - m);
    const _Float16 s2h = (_Float16)EXP2F(fmaf(GAT_ALPHA, sm0, -m));
    f16x8 s1v, s2v;
    #pragma unroll
    for (int i = 0; i < 8; ++i) { s1v[i] = s1h; s2v[i] = s2h; }

    // prologue: stage step 0 into buf 0 (whT via gl16; E tables via compute)
    #pragma unroll
    for (int c = 0; c < 4; ++c)
        gl16(gsrc[c], &whTl[0][ghh][(grg + c) * 4][0]);
    {
        float d0 = esrc[0] - wm;
        e1t[0][ehh][ejl] = (_Float16)EXP2F(d0);
        e2t[0][ehh][ejl] = (_Float16)EXP2F(GAT_ALPHA * d0);
    }
    __syncthreads();   // stage-0 drained (vmcnt before barrier) + E writes visible

    f32x4 acc0 = {0.f, 0.f, 0.f, 0.f};
    f32x4 acc1 = {0.f, 0.f, 0.f, 0.f};
    f32x4 accd = {0.f, 0.f, 0.f, 0.f};

    const u32x4 onesu = {0x3C003C00u, 0x3C003C00u, 0x3C003C00u, 0x3C003C00u};  // fp16 1.0
    const f16x8 ones = __builtin_bit_cast(f16x8, onesu);

    const unsigned long long* arow = adj64 + (size_t)row * 64 + jh * 32;
    unsigned long long au0 = arow[0], au1 = arow[1];
    int cur = 0;

    for (int step = 0; step < 16; ++step) {
        unsigned long long an0 = 0, an1 = 0;
        float vnext = 0.f;
        if (step < 15) {   // issue next-tile loads early (T14)
            #pragma unroll
            for (int c = 0; c < 4; ++c)
                gl16(gsrc[c] + (step + 1) * 128, &whTl[cur ^ 1][ghh][(grg + c) * 4][0]);
            vnext = esrc[(step + 1) * 128];
            an0 = arow[(step + 1) * 2];
            an1 = arow[(step + 1) * 2 + 1];
        }

        #pragma unroll
        for (int kk = 0; kk < 4; ++kk) {
            const int jl = kk * 32 + q * 8;
            const int slot = ((kk * 4 + q) ^ (r & 7)) * 8;   // r9-validated read map
            f16x8 b0 = *(const f16x8*)&whTl[cur][jh][r][slot];
            f16x8 b1 = *(const f16x8*)&whTl[cur][jh][16 + r][slot];
            unsigned int bits =
                (unsigned int)(((kk < 2 ? au0 : au1) >> ((kk & 1) * 32 + q * 8)) & 0xffull);
            // arithmetic mask (bit-identical to the r13 LUT; no LDS read):
            // word k: lo16 = bit(2k), hi16 = bit(2k+1)
            u32x4 mk;
            mk.x = ((bits & 1u)   ? 0xffffu : 0u) | ((bits & 2u)   ? 0xffff0000u : 0u);
            mk.y = ((bits & 4u)   ? 0xffffu : 0u) | ((bits & 8u)   ? 0xffff0000u : 0u);
            mk.z = ((bits & 16u)  ? 0xffffu : 0u) | ((bits & 32u)  ? 0xffff0000u : 0u);
            mk.w = ((bits & 64u)  ? 0xffffu : 0u) | ((bits & 128u) ? 0xffff0000u : 0u);
            f16x8 e1 = *(const f16x8*)&e1t[cur][jh][jl];     // broadcast reads
            f16x8 e2 = *(const f16x8*)&e2t[cur][jh][jl];

            // p = max(s1*E1, s2*E2) = exp2(lrelu(score)-m); packed fp16
            f16x8 pp = __builtin_elementwise_max(s1v * e1, s2v * e2);
            u32x4 pk = __builtin_bit_cast(u32x4, pp) & mk;   // mask
            f16x8 af = __builtin_bit_cast(f16x8, pk);
            __builtin_amdgcn_s_setprio(1);
            acc0 = __builtin_amdgcn_mfma_f32_16x16x32_f16(af, b0, acc0, 0, 0, 0);
            acc1 = __builtin_amdgcn_mfma_f32_16x16x32_f16(af, b1, acc1, 0, 0, 0);
            accd = __builtin_amdgcn_mfma_f32_16x16x32_f16(af, ones, accd, 0, 0, 0);
            __builtin_amdgcn_s_setprio(0);
        }

        if (step < 15) {   // E compute + write-late (before barrier)
            float d1v = vnext - wm;
            e1t[cur ^ 1][ehh][ejl] = (_Float16)EXP2F(d1v);
            e2t[cur ^ 1][ehh][ejl] = (_Float16)EXP2F(GAT_ALPHA * d1v);
        }
        __syncthreads();   // stage(s+1) drained + all waves done with buf[cur]
        au0 = an0;
        au1 = an1;
        cur ^= 1;
    }

    // combine j-halves; red overlaid on dead whTl (r10-validated)
    f32x4* red = (f32x4*)whTl;
    if (jh == 1) {
        f32x4* rp = red + (rt * 64 + lane) * 3;
        rp[0] = acc0;
        rp[1] = acc1;
        rp[2] = accd;
    }
    __syncthreads();
    if (jh == 0) {
        const f32x4* rp = red + (rt * 64 + lane) * 3;
        acc0 += rp[0];
        acc1 += rp[1];
        accd += rp[2];
        // C/D layout (m89-verified, dtype-independent): lane holds D[4q+i][r]
        #pragma unroll
        for (int i = 0; i < 4; ++i) {
            float inv = 1.0f / accd[i];
            int orow = rowbase + rt * 16 + 4 * q + i;
            out[(size_t)orow * 256 + head * 32 + r]      = acc0[i] * inv;
            out[(size_t)orow * 256 + head * 32 + 16 + r] = acc1[i] * inv;
        }
    }
}

extern "C" void kernel_launch(void* const* d_in, const int* in_sizes, int n_in,
                              void* d_out, int out_size, void* d_ws, size_t ws_size,
                              hipStream_t stream) {
    const float* h   = (const float*)d_in[0];
    const int*   adj = (const int*)d_in[1];
    const float* W   = (const float*)d_in[2];
    const float* a   = (const float*)d_in[3];
    float* out = (float*)d_out;

    char* ws = (char*)d_ws;
    unsigned long long* packed = (unsigned long long*)ws;                        // 2 MB
    float* wh1s = (float*)(ws + (2 << 20));                                      // 128 KB
    float* wh2s = (float*)(ws + (2 << 20) + (128 << 10));                        // 128 KB
    unsigned short* whT  = (unsigned short*)(ws + (2 << 20) + (256 << 10));      // 2 MB
    unsigned short* wbfT = (unsigned short*)(ws + (4 << 20) + (256 << 10));      // 128 KB

    const int nwords = 4096 * 64;                       // 262144 u64 words
    k_pack_adj<<<nwords * 64 / 256, 256, 0, stream>>>(adj, packed, nwords, W, wbfT);
    k_wh2<<<dim3(64, 8), 256, 0, stream>>>(h, wbfT, a, wh1s, wh2s, whT);
    k_attn<<<dim3(128, 8), 256, 0, stream>>>(packed, wh1s, wh2s, whT, out);
}

// Round 20
// 69.272 us; speedup vs baseline: 1.0468x; 1.0468x over previous
//
#include <hip/hip_runtime.h>
#include <hip/hip_bf16.h>
#include <stdint.h>

#define GAT_ALPHA 0.2f
#define LOG2E 1.4426950408889634f

typedef __attribute__((ext_vector_type(8))) short bf16x8;
typedef __attribute__((ext_vector_type(8))) _Float16 f16x8;
typedef __attribute__((ext_vector_type(8))) unsigned short ushort8;
typedef __attribute__((ext_vector_type(4))) float f32x4;
typedef __attribute__((ext_vector_type(4))) unsigned int u32x4;

#if __has_builtin(__builtin_amdgcn_exp2f)
#define EXP2F(x) __builtin_amdgcn_exp2f(x)
#else
#define EXP2F(x) exp2f(x)
#endif

// D.lo = bf16(a), D.hi = bf16(b)  (r6-validated)
static __device__ __forceinline__ unsigned int cvt_pk_bf16(float a, float b) {
    unsigned int r;
    asm("v_cvt_pk_bf16_f32 %0, %1, %2" : "=v"(r) : "v"(a), "v"(b));
    return r;
}

// async global->LDS, 16B/lane; dest = wave-uniform base + lane*16 (m104),
// source is PER-LANE (m173 pre-swizzled-source pattern)
static __device__ __forceinline__ void gl16(const void* g, void* l) {
    __builtin_amdgcn_global_load_lds((const __attribute__((address_space(1))) void*)g,
                                     (__attribute__((address_space(3))) void*)l, 16, 0, 0);
}

// ---------------- K0: pack adjacency -> bitmask (r1-validated body) --------
// + blocks 0-31 additionally convert W (r9-validated math). Grid = 65536.
__global__ __launch_bounds__(256) void k_pack_adj(const int* __restrict__ adj,
                                                  unsigned long long* __restrict__ packed,
                                                  int nwords,
                                                  const float* __restrict__ W,
                                                  unsigned short* __restrict__ wbfT) {
    int gid = blockIdx.x * 256 + threadIdx.x;
    int wid = gid >> 6;               // one 64-bit word per wave
    int lane = threadIdx.x & 63;
    if (wid < nwords) {
        int v = adj[(size_t)wid * 64 + lane];
        unsigned long long m = __ballot(v > 0);
        if (lane == 0) packed[wid] = m;
    }
    if (blockIdx.x < 32) {            // fused k_cvtW (r17-validated)
        int idx = (blockIdx.x * 256 + threadIdx.x) * 8;   // over 65536 elements
        int hd = idx >> 8;                                 // head*32 + d
        int i0 = idx & 255;
        int hh = hd >> 5, dd = hd & 31;
        float vv[8];
        #pragma unroll
        for (int k = 0; k < 8; ++k) vv[k] = W[((size_t)hh * 256 + i0 + k) * 32 + dd];
        u32x4 o = { cvt_pk_bf16(vv[0], vv[1]), cvt_pk_bf16(vv[2], vv[3]),
                    cvt_pk_bf16(vv[4], vv[5]), cvt_pk_bf16(vv[6], vv[7]) };
        *(u32x4*)&wbfT[idx] = o;
    }
}

// ---------------- K1: Wh via bf16 MFMA (r17/r18-validated); whT fp16 -------
__global__ __launch_bounds__(256) void k_wh2(const float* __restrict__ hmat,      // [4096][256]
                                             const unsigned short* __restrict__ wbfT, // [8][32][256]
                                             const float* __restrict__ avec,      // [8][64]
                                             float* __restrict__ wh1s,            // [8][4096] *log2e
                                             float* __restrict__ wh2s,            // [8][4096] *log2e
                                             unsigned short* __restrict__ whT) {  // [8][32][4096] fp16
    const int head = blockIdx.y;
    const int nbase = blockIdx.x * 64;
    const int t = threadIdx.x, w = t >> 6, lane = t & 63;
    const int r = lane & 15, q = lane >> 4;
    const int node0 = nbase + w * 16;

    f32x4 acc0 = {0.f, 0.f, 0.f, 0.f};
    f32x4 acc1 = {0.f, 0.f, 0.f, 0.f};
    const float* arow = &hmat[(size_t)(node0 + r) * 256];
    const unsigned short* b0p = &wbfT[((size_t)head * 32 + r) * 256];
    const unsigned short* b1p = b0p + 16 * 256;
    #pragma unroll
    for (int kt = 0; kt < 8; ++kt) {
        const int ko = kt * 32 + q * 8;
        float4 h0 = *(const float4*)&arow[ko];
        float4 h1 = *(const float4*)&arow[ko + 4];
        u32x4 ap = { cvt_pk_bf16(h0.x, h0.y), cvt_pk_bf16(h0.z, h0.w),
                     cvt_pk_bf16(h1.x, h1.y), cvt_pk_bf16(h1.z, h1.w) };
        bf16x8 af = __builtin_bit_cast(bf16x8, ap);
        bf16x8 b0 = *(const bf16x8*)&b0p[ko];
        bf16x8 b1 = *(const bf16x8*)&b1p[ko];
        acc0 = __builtin_amdgcn_mfma_f32_16x16x32_bf16(af, b0, acc0, 0, 0, 0);
        acc1 = __builtin_amdgcn_mfma_f32_16x16x32_bf16(af, b1, acc1, 0, 0, 0);
    }
    // whT in fp16 (RNE; 10-bit mantissa > bf16's 7; |Wh| ~ 20 << 65504)
    auto ph = [](float x) {
        return (unsigned int)__builtin_bit_cast(unsigned short, (_Float16)x);
    };
    unsigned int pk0 = ph(acc0[0]) | (ph(acc0[1]) << 16);
    unsigned int pk1 = ph(acc0[2]) | (ph(acc0[3]) << 16);
    unsigned int pk2 = ph(acc1[0]) | (ph(acc1[1]) << 16);
    unsigned int pk3 = ph(acc1[2]) | (ph(acc1[3]) << 16);
    unsigned long long lo = ((unsigned long long)pk1 << 32) | pk0;
    unsigned long long hi = ((unsigned long long)pk3 << 32) | pk2;
    *(unsigned long long*)&whT[((size_t)head * 32 + r) * 4096 + node0 + q * 4] = lo;
    *(unsigned long long*)&whT[((size_t)head * 32 + 16 + r) * 4096 + node0 + q * 4] = hi;

    float a1lo = avec[head * 64 + r],      a1hi = avec[head * 64 + 16 + r];
    float a2lo = avec[head * 64 + 32 + r], a2hi = avec[head * 64 + 48 + r];
    f32x4 d1, d2;
    #pragma unroll
    for (int i = 0; i < 4; ++i) {
        d1[i] = fmaf(acc0[i], a1lo, acc1[i] * a1hi);
        d2[i] = fmaf(acc0[i], a2lo, acc1[i] * a2hi);
    }
    #pragma unroll
    for (int s = 1; s < 16; s <<= 1) {
        #pragma unroll
        for (int i = 0; i < 4; ++i) {
            d1[i] += __shfl_xor(d1[i], s);
            d2[i] += __shfl_xor(d2[i], s);
        }
    }
    if (r == 0) {
        f32x4 o1 = d1 * LOG2E, o2 = d2 * LOG2E;
        *(f32x4*)&wh1s[(size_t)head * 4096 + node0 + q * 4] = o1;
        *(f32x4*)&wh2s[(size_t)head * 4096 + node0 + q * 4] = o2;
    }
}

// ---------------- K2: fused masked softmax + PV via f16 MFMA ---------------
// r18-PASSING kernel VERBATIM: exp factored out of the inner loop
// (p = max(s1*E1[j], s2*E2[j]), per-j tables computed during staging),
// 256-entry mask LUT (ds_read overlaps under latency slack — r19 proved
// arithmetic masks are slower), gl16 pre-swizzled staging, double buffer,
// XOR read map, red overlay, setprio.
__global__ __launch_bounds__(256, 4) void k_attn(const unsigned long long* __restrict__ adj64, // [4096][64]
                                                 const float* __restrict__ wh1s,
                                                 const float* __restrict__ wh2s,
                                                 const unsigned short* __restrict__ whT,
                                                 float* __restrict__ out) {                    // [4096][256]
    const int head = blockIdx.y;
    const int rowbase = blockIdx.x * 32;
    const int t = threadIdx.x;
    const int w = t >> 6;
    const int lane = t & 63;
    const int rt = w & 1;        // row-tile
    const int jh = w >> 1;       // j-half
    const int r = lane & 15;     // MFMA A row / B col
    const int q = lane >> 4;     // k-quarter
    const int row = rowbase + rt * 16 + r;

    __shared__ unsigned short whTl[2][2][32][128];   // [buf][jhalf][d][phys slots]
    __shared__ _Float16 e1t[2][2][128];              // [buf][jhalf][j] exp tables
    __shared__ _Float16 e2t[2][2][128];
    __shared__ float wmxb[4];
    __shared__ unsigned int lut[256][4] __attribute__((aligned(16)));

    // mask LUT (r13/r17-validated): byte -> 4 words; bit(2k)->lo, bit(2k+1)->hi
    {
        unsigned int b = t;
        lut[t][0] = ((b & 1u)   ? 0xffffu : 0u) | ((b & 2u)   ? 0xffff0000u : 0u);
        lut[t][1] = ((b & 4u)   ? 0xffffu : 0u) | ((b & 8u)   ? 0xffff0000u : 0u);
        lut[t][2] = ((b & 16u)  ? 0xffffu : 0u) | ((b & 32u)  ? 0xffff0000u : 0u);
        lut[t][3] = ((b & 64u)  ? 0xffffu : 0u) | ((b & 128u) ? 0xffff0000u : 0u);
    }

    // per-lane pre-swizzled global sources for this wave's 4 staging calls
    const int ghh = w >> 1;          // j-half this wave stages
    const int grg = (w & 1) * 4;     // row-group base
    const unsigned short* gsrc[4];
    #pragma unroll
    for (int c = 0; c < 4; ++c) {
        int d = (grg + c) * 4 + (lane >> 4);
        int p = lane & 15;
        int ls = (p & 8) | ((p ^ d) & 7);
        gsrc[c] = whT + ((size_t)(head * 32 + d)) * 4096 + ghh * 2048 + ls * 8;
    }
    const float* wh2p = &wh2s[(size_t)head * 4096];
    // E-table staging assignment: thread t -> half ehh, j-local ejl
    const int ehh = t >> 7;
    const int ejl = t & 127;
    const float* esrc = wh2p + ehh * 2048 + ejl;

    // per-head max of wh2 (r7-validated prepass) — needed BEFORE E staging
    float lm = -INFINITY;
    #pragma unroll
    for (int kk = 0; kk < 4; ++kk) {
        float4 v = *(const float4*)&wh2p[kk * 1024 + t * 4];
        lm = fmaxf(fmaxf(lm, fmaxf(v.x, v.y)), fmaxf(v.z, v.w));
    }
    #pragma unroll
    for (int s = 1; s < 64; s <<= 1) lm = fmaxf(lm, __shfl_xor(lm, s));
    if (lane == 0) wmxb[w] = lm;
    __syncthreads();   // wmxb + lut ready
    const float wm = fmaxf(fmaxf(wmxb[0], wmxb[1]), fmaxf(wmxb[2], wmxb[3]));

    // per-row constants (log2-scaled). m = max(sm0, a*sm0) -> max(s1,s2)=1.
    const float wh1 = wh1s[(size_t)head * 4096 + row];
    const float sm0 = wh1 + wm;
    const float m = fmaxf(sm0, GAT_ALPHA * sm0);
    const _Float16 s1h = (_Float16)EXP2F(sm0 - m);
    const _Float16 s2h = (_Float16)EXP2F(fmaf(GAT_ALPHA, sm0, -m));
    f16x8 s1v, s2v;
    #pragma unroll
    for (int i = 0; i < 8; ++i) { s1v[i] = s1h; s2v[i] = s2h; }

    // prologue: stage step 0 into buf 0 (whT via gl16; E tables via compute)
    #pragma unroll
    for (int c = 0; c < 4; ++c)
        gl16(gsrc[c], &whTl[0][ghh][(grg + c) * 4][0]);
    {
        float d0 = esrc[0] - wm;
        e1t[0][ehh][ejl] = (_Float16)EXP2F(d0);
        e2t[0][ehh][ejl] = (_Float16)EXP2F(GAT_ALPHA * d0);
    }
    __syncthreads();   // stage-0 drained (vmcnt before barrier) + E writes visible

    f32x4 acc0 = {0.f, 0.f, 0.f, 0.f};
    f32x4 acc1 = {0.f, 0.f, 0.f, 0.f};
    f32x4 accd = {0.f, 0.f, 0.f, 0.f};

    const u32x4 onesu = {0x3C003C00u, 0x3C003C00u, 0x3C003C00u, 0x3C003C00u};  // fp16 1.0
    const f16x8 ones = __builtin_bit_cast(f16x8, onesu);

    const unsigned long long* arow = adj64 + (size_t)row * 64 + jh * 32;
    unsigned long long au0 = arow[0], au1 = arow[1];
    int cur = 0;

    for (int step = 0; step < 16; ++step) {
        unsigned long long an0 = 0, an1 = 0;
        float vnext = 0.f;
        if (step < 15) {   // issue next-tile loads early (T14)
            #pragma unroll
            for (int c = 0; c < 4; ++c)
                gl16(gsrc[c] + (step + 1) * 128, &whTl[cur ^ 1][ghh][(grg + c) * 4][0]);
            vnext = esrc[(step + 1) * 128];
            an0 = arow[(step + 1) * 2];
            an1 = arow[(step + 1) * 2 + 1];
        }

        #pragma unroll
        for (int kk = 0; kk < 4; ++kk) {
            const int jl = kk * 32 + q * 8;
            const int slot = ((kk * 4 + q) ^ (r & 7)) * 8;   // r9-validated read map
            f16x8 b0 = *(const f16x8*)&whTl[cur][jh][r][slot];
            f16x8 b1 = *(const f16x8*)&whTl[cur][jh][16 + r][slot];
            unsigned int bits =
                (unsigned int)(((kk < 2 ? au0 : au1) >> ((kk & 1) * 32 + q * 8)) & 0xffull);
            u32x4 mk = *(const u32x4*)lut[bits];
            f16x8 e1 = *(const f16x8*)&e1t[cur][jh][jl];     // broadcast reads
            f16x8 e2 = *(const f16x8*)&e2t[cur][jh][jl];

            // p = max(s1*E1, s2*E2) = exp2(lrelu(score)-m); packed fp16
            f16x8 pp = __builtin_elementwise_max(s1v * e1, s2v * e2);
            u32x4 pk = __builtin_bit_cast(u32x4, pp) & mk;   // mask
            f16x8 af = __builtin_bit_cast(f16x8, pk);
            __builtin_amdgcn_s_setprio(1);
            acc0 = __builtin_amdgcn_mfma_f32_16x16x32_f16(af, b0, acc0, 0, 0, 0);
            acc1 = __builtin_amdgcn_mfma_f32_16x16x32_f16(af, b1, acc1, 0, 0, 0);
            accd = __builtin_amdgcn_mfma_f32_16x16x32_f16(af, ones, accd, 0, 0, 0);
            __builtin_amdgcn_s_setprio(0);
        }

        if (step < 15) {   // E compute + write-late (before barrier)
            float d1v = vnext - wm;
            e1t[cur ^ 1][ehh][ejl] = (_Float16)EXP2F(d1v);
            e2t[cur ^ 1][ehh][ejl] = (_Float16)EXP2F(GAT_ALPHA * d1v);
        }
        __syncthreads();   // stage(s+1) drained + all waves done with buf[cur]
        au0 = an0;
        au1 = an1;
        cur ^= 1;
    }

    // combine j-halves; red overlaid on dead whTl (r10-validated)
    f32x4* red = (f32x4*)whTl;
    if (jh == 1) {
        f32x4* rp = red + (rt * 64 + lane) * 3;
        rp[0] = acc0;
        rp[1] = acc1;
        rp[2] = accd;
    }
    __syncthreads();
    if (jh == 0) {
        const f32x4* rp = red + (rt * 64 + lane) * 3;
        acc0 += rp[0];
        acc1 += rp[1];
        accd += rp[2];
        // C/D layout (m89-verified, dtype-independent): lane holds D[4q+i][r]
        #pragma unroll
        for (int i = 0; i < 4; ++i) {
            float inv = 1.0f / accd[i];
            int orow = rowbase + rt * 16 + 4 * q + i;
            out[(size_t)orow * 256 + head * 32 + r]      = acc0[i] * inv;
            out[(size_t)orow * 256 + head * 32 + 16 + r] = acc1[i] * inv;
        }
    }
}

extern "C" void kernel_launch(void* const* d_in, const int* in_sizes, int n_in,
                              void* d_out, int out_size, void* d_ws, size_t ws_size,
                              hipStream_t stream) {
    const float* h   = (const float*)d_in[0];
    const int*   adj = (const int*)d_in[1];
    const float* W   = (const float*)d_in[2];
    const float* a   = (const float*)d_in[3];
    float* out = (float*)d_out;

    char* ws = (char*)d_ws;
    unsigned long long* packed = (unsigned long long*)ws;                        // 2 MB
    float* wh1s = (float*)(ws + (2 << 20));                                      // 128 KB
    float* wh2s = (float*)(ws + (2 << 20) + (128 << 10));                        // 128 KB
    unsigned short* whT  = (unsigned short*)(ws + (2 << 20) + (256 << 10));      // 2 MB
    unsigned short* wbfT = (unsigned short*)(ws + (4 << 20) + (256 << 10));      // 128 KB

    const int nwords = 4096 * 64;                       // 262144 u64 words
    k_pack_adj<<<nwords * 64 / 256, 256, 0, stream>>>(adj, packed, nwords, W, wbfT);
    k_wh2<<<dim3(64, 8), 256, 0, stream>>>(h, wbfT, a, wh1s, wh2s, whT);
    k_attn<<<dim3(128, 8), 256, 0, stream>>>(packed, wh1s, wh2s, whT, out);
}